// Round 1
// baseline (12600.558 us; speedup 1.0000x reference)
//
#include <hip/hip_runtime.h>
#include <stdint.h>

// ---------------- problem constants ----------------
#define BSZ 64
#define TSEQ 512
#define ESZ 512
#define HSZ 512
#define KTAG 12
#define START_TAG 10
#define STOP_TAG 11

// ---------------- persistent-kernel config ----------------
#define NWG 256
#define BLK 256

// LDS layout (in floats)
#define W_OFF 0        // 32768 floats: W[e][j] quad-XOR-swizzled
#define X_OFF 32768    // 4096 floats: 2x 64e x 32c chunk buffers / reduction scratch / hloc
#define CST_OFF 36864  // 256: c-state [uu][c]
#define BIAS_OFF 37120 // 32
#define WOUT_OFF 37152 // 96: W_out slice [k][uu]
#define SL_OFF 37248   // 32 ints
#define TOK_OFF 37280  // 32 ints
#define BROW_OFF 37312 // 32 ints
#define MSL_OFF 37344  // 1 int
#define SMEM_FLOATS 37352
#define SMEM_BYTES (SMEM_FLOATS * 4)

// workspace layout (bytes)
#define BAR_BYTES 4096
#define FEATS_OFF 4096
#define FEATS_BYTES (BSZ * TSEQ * KTAG * 8)            // 3145728
#define HBUF_OFF (FEATS_OFF + FEATS_BYTES)             // 3149824
#define HBUF_BYTES (2 * HSZ * 128 * 4)                 // 524288
#define BPS_OFF (HBUF_OFF + HBUF_BYTES)                // 3674112
#define BPS_BYTES (TSEQ * BSZ * KTAG)                  // 393216

#define FIX_SCALE 4294967296.0
#define FIX_INV 2.3283064365386963e-10

// two-level global barrier: bar[0]=flag, bar[16]=root cnt, bar[32+g*16]=group cnt
__device__ __forceinline__ void gbar(unsigned* bar, unsigned idx, int g) {
  __syncthreads();
  if (threadIdx.x == 0) {
    bool setter = false;
    __builtin_amdgcn_fence(__ATOMIC_RELEASE, "agent");
    unsigned o = __hip_atomic_fetch_add(&bar[32 + g * 16], 1u, __ATOMIC_RELAXED,
                                        __HIP_MEMORY_SCOPE_AGENT);
    if (o == idx * 8u - 1u) {
      unsigned r = __hip_atomic_fetch_add(&bar[16], 1u, __ATOMIC_RELAXED,
                                          __HIP_MEMORY_SCOPE_AGENT);
      if (r == idx * 32u - 1u) {
        __builtin_amdgcn_fence(__ATOMIC_ACQUIRE, "agent");
        __hip_atomic_store(&bar[0], idx, __ATOMIC_RELAXED, __HIP_MEMORY_SCOPE_AGENT);
        setter = true;
      }
    }
    if (!setter) {
      while (__hip_atomic_load(&bar[0], __ATOMIC_RELAXED, __HIP_MEMORY_SCOPE_AGENT) < idx) {}
      __builtin_amdgcn_fence(__ATOMIC_ACQUIRE, "agent");
    }
  }
  __syncthreads();
}

__device__ __forceinline__ float sigm(float x) { return 1.f / (1.f + expf(-x)); }

// stage 8 floats of X[c][e-range] into registers (x-part: embed gather; h-part: ping-pong h)
#define STAGE_LOAD(KK)                                                        \
  {                                                                           \
    int kq = (KK);                                                            \
    if (kq < 8) {                                                             \
      int tok = tokS[cS];                                                     \
      if (tok >= 0) {                                                         \
        const float* rp = embed + (size_t)tok * 512 + kq * 64 + eblk * 8;     \
        float4 a0 = *(const float4*)(rp);                                     \
        float4 a1 = *(const float4*)(rp + 4);                                 \
        st[0] = a0.x; st[1] = a0.y; st[2] = a0.z; st[3] = a0.w;               \
        st[4] = a1.x; st[5] = a1.y; st[6] = a1.z; st[7] = a1.w;               \
      } else {                                                                \
        _Pragma("unroll") for (int m = 0; m < 8; ++m) st[m] = 0.f;            \
      }                                                                       \
    } else {                                                                  \
      int ub = (kq - 8) * 64 + eblk * 8;                                      \
      _Pragma("unroll") for (int m = 0; m < 8; ++m)                           \
        st[m] = hcur[(ub + m) * 128 + ch0 + cS];                              \
    }                                                                         \
  }

#define RED_WR(SL)                                                            \
  _Pragma("unroll") for (int a = 0; a < 8; ++a)                               \
  _Pragma("unroll") for (int b2 = 0; b2 < 8; ++b2)                            \
      xS[(SL) * 1024 + (jt * 8 + a) * 32 + ct2 * 8 + b2] = acc[a][b2];

#define RED_ADD(SL)                                                           \
  _Pragma("unroll") for (int a = 0; a < 8; ++a)                               \
  _Pragma("unroll") for (int b2 = 0; b2 < 8; ++b2)                            \
      acc[a][b2] += xS[(SL) * 1024 + (jt * 8 + a) * 32 + ct2 * 8 + b2];

__global__ __launch_bounds__(BLK, 1) void lstm_all(
    const int* __restrict__ sentence, const int* __restrict__ seq_lens,
    const float* __restrict__ embed, const float* __restrict__ Wi_f,
    const float* __restrict__ Wh_f, const float* __restrict__ b_f,
    const float* __restrict__ Wi_b, const float* __restrict__ Wh_b,
    const float* __restrict__ b_b, const float* __restrict__ h0,
    const float* __restrict__ c0, const float* __restrict__ W_out,
    unsigned long long* __restrict__ featsFix, float* __restrict__ hbuf,
    unsigned* __restrict__ bar) {
  extern __shared__ float sm[];
  float* wS = sm + W_OFF;
  float* xS = sm + X_OFF;
  float* cstS = sm + CST_OFF;
  float* biasS = sm + BIAS_OFF;
  float* woutS = sm + WOUT_OFF;
  int* slS = (int*)(sm + SL_OFF);
  int* tokS = (int*)(sm + TOK_OFF);
  int* browS = (int*)(sm + BROW_OFF);
  int* mslS = (int*)(sm + MSL_OFF);

  const int tid = threadIdx.x;
  const int bid = blockIdx.x;
  const int ut = bid & 63, ct = bid >> 6;
  const int u0 = ut * 8, ch0 = ct * 32, dir = ct >> 1;
  const int g = bid & 31;
  const float* Wi = dir ? Wi_b : Wi_f;
  const float* Wh = dir ? Wh_b : Wh_f;
  const float* bb = dir ? b_b : b_f;

  // ---- load weight slice into LDS: w[e][j], quad-swizzled pq = (j>>2)^(e&7) ----
  for (int j = 0; j < 32; ++j) {
    int row = (j >> 3) * 512 + u0 + (j & 7);
    for (int ee = tid; ee < 1024; ee += BLK) {
      float v = (ee < 512) ? Wi[row * 512 + ee] : Wh[row * 512 + (ee - 512)];
      wS[ee * 32 + (((j >> 2) ^ (ee & 7)) << 2) + (j & 3)] = v;
    }
  }
  if (tid < 32) {
    int b = ((ct & 1) << 5) + tid;
    browS[tid] = b;
    slS[tid] = seq_lens[b];
    tokS[tid] = -1;
  }
  if (tid < 96) woutS[tid] = W_out[(tid >> 3) * 1024 + dir * 512 + u0 + (tid & 7)];
  if (tid < 32) biasS[tid] = bb[(tid >> 3) * 512 + u0 + (tid & 7)];
  __syncthreads();
  if (tid == 0) {
    int m = 0;
    for (int c = 0; c < 32; ++c) m = max(m, slS[c]);
    *mslS = m;
  }
  // ---- state init: c in LDS, h[0] to global ping-pong (transposed [u][ch]) ----
  {
    int uu = tid >> 5, c = tid & 31;
    int b = browS[c];
    cstS[uu * 32 + c] = c0[(dir * 64 + b) * 512 + u0 + uu];
    hbuf[(u0 + uu) * 128 + ch0 + c] = h0[(dir * 64 + b) * 512 + u0 + uu];
  }
  gbar(bar, 1, g);

  const int es = tid >> 4, tp = tid & 15, jt = tp & 3, ct2 = tp >> 2;
  const int cS = tid & 31, eblk = tid >> 5;
  const int maxsl = *mslS;

  for (int t = 0; t < TSEQ; ++t) {
    if (t < maxsl) {
      const float* hcur = hbuf + (t & 1) * 65536;
      float* hnxt = hbuf + ((t + 1) & 1) * 65536;
      if (tid < 32) {
        int sl = slS[tid];
        int tok = -1;
        if (t < sl) {
          int pos = dir ? (sl - 1 - t) : t;
          tok = sentence[browS[tid] * 512 + pos];
        }
        tokS[tid] = tok;
      }
      __syncthreads();
      float acc[8][8];
#pragma unroll
      for (int a = 0; a < 8; ++a)
#pragma unroll
        for (int b2 = 0; b2 < 8; ++b2) acc[a][b2] = 0.f;
      float st[8];
      STAGE_LOAD(0)
      for (int k = 0; k < 16; ++k) {
        float* xb = xS + (k & 1) * 2048;
        // store chunk k (staged in regs) into LDS, swizzled [e][c]
#pragma unroll
        for (int m = 0; m < 8; ++m) {
          int eloc = eblk * 8 + m;
          xb[eloc * 32 + ((((cS >> 2) ^ (m & 7)) << 2) | (cS & 3))] = st[m];
        }
        if (k < 15) STAGE_LOAD(k + 1)
        __syncthreads();
        // compute chunk k: 8j x 8c register tile, e strided by 16 across es-lanes
        {
          const int esw = es & 7;
#pragma unroll
          for (int i = 0; i < 4; ++i) {
            int e = k * 64 + es + 16 * i;
            int eloc = es + 16 * i;
            const float4 w0 = *(const float4*)(wS + e * 32 + (((jt * 2) ^ esw) << 2));
            const float4 w1 = *(const float4*)(wS + e * 32 + (((jt * 2 + 1) ^ esw) << 2));
            const float4 x0 = *(const float4*)(xb + eloc * 32 + (((ct2 * 2) ^ esw) << 2));
            const float4 x1 = *(const float4*)(xb + eloc * 32 + (((ct2 * 2 + 1) ^ esw) << 2));
            float wv[8] = {w0.x, w0.y, w0.z, w0.w, w1.x, w1.y, w1.z, w1.w};
            float xv[8] = {x0.x, x0.y, x0.z, x0.w, x1.x, x1.y, x1.z, x1.w};
#pragma unroll
            for (int a = 0; a < 8; ++a)
#pragma unroll
              for (int b2 = 0; b2 < 8; ++b2)
                acc[a][b2] = fmaf(wv[a], xv[b2], acc[a][b2]);
          }
        }
      }
      // ---- deterministic log-tree reduction of 16 es-partials (scratch = xS) ----
      __syncthreads();
      if (es >= 8 && es < 12) { RED_WR(es - 8) }
      __syncthreads();
      if (es < 4) { RED_ADD(es) }
      __syncthreads();
      if (es >= 12) { RED_WR(es - 12) }
      __syncthreads();
      if (es >= 4 && es < 8) { RED_ADD(es - 4) }
      __syncthreads();
      if (es >= 4 && es < 8) { RED_WR(es - 4) }
      __syncthreads();
      if (es < 4) { RED_ADD(es) }
      __syncthreads();
      if (es == 2 || es == 3) { RED_WR(es - 2) }
      __syncthreads();
      if (es < 2) { RED_ADD(es) }
      __syncthreads();
      if (es == 1) { RED_WR(0) }
      __syncthreads();
      if (es == 0) {
        RED_ADD(0)
#pragma unroll
        for (int a = 0; a < 8; ++a)
#pragma unroll
          for (int b2 = 0; b2 < 8; ++b2)
            xS[(jt * 8 + a) * 32 + ct2 * 8 + b2] = acc[a][b2];
      }
      __syncthreads();
      // ---- epilogue: gates -> c,h ----
      {
        int uu = tid >> 5, c = tid & 31;
        float iv = xS[(uu)*32 + c] + biasS[uu];
        float fv = xS[(8 + uu) * 32 + c] + biasS[8 + uu];
        float gv = xS[(16 + uu) * 32 + c] + biasS[16 + uu];
        float ov = xS[(24 + uu) * 32 + c] + biasS[24 + uu];
        float cn = sigm(fv) * cstS[uu * 32 + c] + sigm(iv) * tanhf(gv);
        float hn = sigm(ov) * tanhf(cn);
        cstS[uu * 32 + c] = cn;
        hnxt[(u0 + uu) * 128 + ch0 + c] = hn;
        xS[1024 + uu * 32 + c] = hn;  // hloc for feats
      }
      __syncthreads();
      // ---- feats partial: fixed-point atomic accumulate ----
      for (int base = 0; base < 384; base += 256) {
        int idx = base + tid;
        if (idx < 384) {
          int c = idx / 12, k = idx % 12;
          int sl = slS[c];
          if (t < sl) {
            float p = 0.f;
#pragma unroll
            for (int uu = 0; uu < 8; ++uu)
              p += xS[1024 + uu * 32 + c] * woutS[k * 8 + uu];
            int tt = dir ? (sl - 1 - t) : t;
            double y = (double)p * FIX_SCALE;
            long long q = (long long)(y + (y >= 0.0 ? 0.5 : -0.5));
            atomicAdd(&featsFix[((size_t)browS[c] * 512 + tt) * 12 + k],
                      (unsigned long long)q);
          }
        }
      }
    }
    gbar(bar, (unsigned)(t + 2), g);
  }
}

__global__ __launch_bounds__(768) void viterbi_kernel(
    const int* __restrict__ seq_lens, const float* __restrict__ b_out,
    const float* __restrict__ transitions,
    const unsigned long long* __restrict__ featsFix,
    unsigned char* __restrict__ bps, float* __restrict__ out) {
  __shared__ float fvL[64 * 13];
  __shared__ float tmL[64 * 13];
  __shared__ float trL[144];
  __shared__ float boutL[12];
  __shared__ int slL[64];
  __shared__ unsigned char tagL[64 * 512];
  const int tid = threadIdx.x;
  const int b = tid & 63, k = tid >> 6;  // k in [0,12)
  if (tid < 144) trL[tid] = transitions[tid];
  if (tid < 12) boutL[tid] = b_out[tid];
  if (tid < 64) slL[tid] = seq_lens[tid];
  fvL[b * 13 + k] = (k == START_TAG) ? 0.f : -10000.f;
  __syncthreads();
  for (int t = 0; t < TSEQ; ++t) {
    bool m = t < slL[b];
    float best = fvL[b * 13 + 0] + trL[k * 12 + 0];
    int arg = 0;
#pragma unroll
    for (int p = 1; p < 12; ++p) {
      float v = fvL[b * 13 + p] + trL[k * 12 + p];
      if (v > best) { best = v; arg = p; }
    }
    long long fx = (long long)featsFix[((size_t)b * 512 + t) * 12 + k];
    float feat = (float)((double)fx * FIX_INV) + boutL[k];
    float nv = m ? (best + feat) : fvL[b * 13 + k];
    bps[((size_t)t * 64 + b) * 12 + k] = (unsigned char)(m ? arg : k);
    __syncthreads();
    fvL[b * 13 + k] = nv;
    __syncthreads();
  }
  tmL[b * 13 + k] = fvL[b * 13 + k] + trL[STOP_TAG * 12 + k];
  __syncthreads();
  if (tid < 64) {
    float best = tmL[tid * 13 + 0];
    int arg = 0;
    for (int kk = 1; kk < 12; ++kk) {
      float v = tmL[tid * 13 + kk];
      if (v > best) { best = v; arg = kk; }
    }
    out[tid] = best;
    int tag = arg;
    const uint32_t* rowp = (const uint32_t*)bps;
    uint32_t r0, r1, r2;
    { int off = (511 * 64 + tid) * 3; r0 = rowp[off]; r1 = rowp[off + 1]; r2 = rowp[off + 2]; }
    for (int t = 511; t >= 0; --t) {
      uint32_t n0 = 0, n1 = 0, n2 = 0;
      if (t > 0) {
        int off = ((t - 1) * 64 + tid) * 3;
        n0 = rowp[off]; n1 = rowp[off + 1]; n2 = rowp[off + 2];
      }
      tagL[tid * 512 + t] = (unsigned char)tag;
      uint32_t sel = (tag < 4) ? (r0 >> (tag * 8))
                   : (tag < 8) ? (r1 >> ((tag - 4) * 8))
                               : (r2 >> ((tag - 8) * 8));
      tag = (int)(sel & 0xffu);
      r0 = n0; r1 = n1; r2 = n2;
    }
  }
  __syncthreads();
  for (int idx = tid; idx < 64 * 512; idx += 768)
    out[64 + idx] = (float)tagL[idx];
}

extern "C" void kernel_launch(void* const* d_in, const int* in_sizes, int n_in,
                              void* d_out, int out_size, void* d_ws, size_t ws_size,
                              hipStream_t stream) {
  (void)in_sizes; (void)n_in; (void)out_size; (void)ws_size;
  const int* sentence = (const int*)d_in[0];
  const int* seq_lens = (const int*)d_in[1];
  const float* embed = (const float*)d_in[2];
  const float* Wi_f = (const float*)d_in[3];
  const float* Wh_f = (const float*)d_in[4];
  const float* b_f = (const float*)d_in[5];
  const float* Wi_b = (const float*)d_in[6];
  const float* Wh_b = (const float*)d_in[7];
  const float* b_b = (const float*)d_in[8];
  const float* h0 = (const float*)d_in[9];
  const float* c0 = (const float*)d_in[10];
  const float* W_out = (const float*)d_in[11];
  const float* b_out = (const float*)d_in[12];
  const float* trans = (const float*)d_in[13];

  char* ws = (char*)d_ws;
  unsigned* bar = (unsigned*)ws;
  unsigned long long* featsFix = (unsigned long long*)(ws + FEATS_OFF);
  float* hbuf = (float*)(ws + HBUF_OFF);
  unsigned char* bps = (unsigned char*)(ws + BPS_OFF);

  hipMemsetAsync(d_ws, 0, FEATS_OFF + FEATS_BYTES, stream);

  hipFuncSetAttribute((const void*)lstm_all,
                      hipFuncAttributeMaxDynamicSharedMemorySize, SMEM_BYTES);
  void* kargs[] = {(void*)&sentence, (void*)&seq_lens, (void*)&embed,
                   (void*)&Wi_f,     (void*)&Wh_f,     (void*)&b_f,
                   (void*)&Wi_b,     (void*)&Wh_b,     (void*)&b_b,
                   (void*)&h0,       (void*)&c0,       (void*)&W_out,
                   (void*)&featsFix, (void*)&hbuf,     (void*)&bar};
  hipLaunchCooperativeKernel((const void*)lstm_all, dim3(NWG), dim3(BLK), kargs,
                             SMEM_BYTES, stream);
  viterbi_kernel<<<dim3(1), dim3(768), 0, stream>>>(seq_lens, b_out, trans,
                                                    featsFix, bps, (float*)d_out);
}